// Round 18
// baseline (311.412 us; speedup 1.0000x reference)
//
#include <hip/hip_runtime.h>
#include <hip/hip_bf16.h>

#define B_ 64
#define H1_ 64
#define W1_ 32
#define Hp 70
#define Wp 35
#define C_ 128
#define NH_ 4
#define HD_ 32
#define WS_ 7
#define SS_ 3
#define NWC_ 5
#define NWIN_ 50
#define NTOK_ 49
#define SCALE_ 0.17677669529663687f

typedef __hip_bfloat16 bf16;
typedef __attribute__((ext_vector_type(8))) short sh8;     // 8 bf16 = 4 VGPR
typedef __attribute__((ext_vector_type(4))) float f32x4;   // MFMA acc

__device__ __forceinline__ float bs2f(short s) {
    unsigned int u = ((unsigned int)(unsigned short)s) << 16;
    float f; __builtin_memcpy(&f, &u, 4); return f;
}
__device__ __forceinline__ short f2bs(float f) {
    bf16 h = __float2bfloat16(f);
    return *reinterpret_cast<short*>(&h);
}
__device__ __forceinline__ unsigned pk2(float lo, float hi) {
    return ((unsigned)(unsigned short)f2bs(hi) << 16) | (unsigned)(unsigned short)f2bs(lo);
}

// ---- prep: fp32 weights -> bf16 [N][K] + TRANSPOSED attn-bias table ----
// ws layout (shorts): wq[384][128] @0 ; wp[128][128] @49152 ; w1[512][128] @65536 ;
//                     w2[128][512] @131072 ; btT[4][64 k][64 q] @196608 (ends 212992)
__global__ void prep_k(const float* __restrict__ qkvw, const float* __restrict__ projw,
                       const float* __restrict__ f1w, const float* __restrict__ f2w,
                       const float* __restrict__ rpb,
                       short* __restrict__ ws) {
    int tid = blockIdx.x * 256 + threadIdx.x;          // 832*256 = 212992 total
    if (tid < 49152) {
        int n = tid >> 7, k = tid & 127;               // qkv_w [128][384]
        ws[tid] = f2bs(qkvw[k*384 + n]);
    } else if (tid < 65536) {
        int t = tid - 49152; int n = t >> 7, k = t & 127;   // proj_w [128][128]
        ws[tid] = f2bs(projw[k*128 + n]);
    } else if (tid < 131072) {
        int t = tid - 65536; int n = t >> 7, k = t & 127;   // fc1_w [128][512]
        ws[tid] = f2bs(f1w[k*512 + n]);
    } else if (tid < 196608) {
        int t = tid - 131072; int n = t >> 9, k = t & 511;  // fc2_w [512][128]
        ws[tid] = f2bs(f2w[k*128 + n]);
    } else if (tid < 212992) {
        int t = tid - 196608;                               // btT [4][k][q]
        int h = t >> 12, k = (t >> 6) & 63, q = t & 63;
        float val = -30000.f;                               // padded rows/cols
        if (q < NTOK_ && k < NTOK_) {
            int ri = q / WS_, ci = q % WS_, rj = k / WS_, cj = k % WS_;
            val = rpb[((ri - rj + 6)*13 + (ci - cj + 6))*4 + h];
        }
        ws[tid] = f2bs(val);
    }
}

// ---- win_attn, 8 waves; swapped-QK^T lane-local softmax, in-register P ----
// LDS map (70656 B, 2 blocks/CU):
//   [0,17408)       q_s  bf16[64][136]
//   [17408,34816)   k_s  bf16[64][136]  -> cat (phase C)
//   [34816,53248)   vt   bf16[128][72]  (V transposed: [ch][tok])
//   [53248,70656)   xsp  bf16[64][136]  (phase A only)
__global__ __launch_bounds__(512, 4) void win_attn(
    const float* __restrict__ x,
    const float* __restrict__ n1g, const float* __restrict__ n1b,
    const float* __restrict__ qkvb, const short* __restrict__ btT,
    const float* __restrict__ projb,
    const short* __restrict__ wq, const short* __restrict__ wp,
    float* __restrict__ out)
{
    __shared__ char smem[70656];
    short* q_s = (short*)smem;
    short* k_s = (short*)(smem + 17408);
    short* cat = (short*)(smem + 17408);
    short* vt  = (short*)(smem + 34816);
    short* xsp = (short*)(smem + 53248);

    const int tid = threadIdx.x;
    const int lane = tid & 63, wv = tid >> 6;
    const int l15 = lane & 15, l4 = lane >> 4;
    const int mt = wv & 3, hg = wv >> 2;
    const int bw = blockIdx.x;
    const int b = bw / NWIN_, win = bw % NWIN_;
    const int wr = win / NWC_, wc = win % NWC_;

    // ---- phase A1: gather + LN1, float4; 2 rows/wave/iter ----
    #pragma unroll
    for (int it = 0; it < 4; ++it) {
        int n = it*16 + wv*2 + (lane >> 5);
        int r = n / WS_, cc = n % WS_;
        int h = (wr*WS_ + r + SS_) % Hp;
        int w = (wc*WS_ + cc + SS_) % Wp;
        int c0 = (lane & 31) * 4;
        float4 v = make_float4(0.f, 0.f, 0.f, 0.f);
        if (n < NTOK_ && h < H1_ && w < W1_)
            v = *(const float4*)(x + ((size_t)(b*H1_*W1_ + h*W1_ + w))*C_ + c0);
        float s  = v.x + v.y + v.z + v.w;
        float sq = v.x*v.x + v.y*v.y + v.z*v.z + v.w*v.w;
        #pragma unroll
        for (int off = 1; off < 32; off <<= 1) {
            s  += __shfl_xor(s, off);
            sq += __shfl_xor(sq, off);
        }
        float mean = s * (1.f/128.f);
        float var  = sq * (1.f/128.f) - mean*mean;   // biased var (jnp.var)
        float rstd = rsqrtf(var + 1e-5f);
        short4 o;
        o.x = f2bs((v.x - mean)*rstd*n1g[c0+0] + n1b[c0+0]);
        o.y = f2bs((v.y - mean)*rstd*n1g[c0+1] + n1b[c0+1]);
        o.z = f2bs((v.z - mean)*rstd*n1g[c0+2] + n1b[c0+2]);
        o.w = f2bs((v.w - mean)*rstd*n1g[c0+3] + n1b[c0+3]);
        *(short4*)(xsp + n*136 + c0) = o;
    }
    __syncthreads();

    // ---- phase A2: qkv, wave = 3 n-tiles x 4 m-tiles x K=128 ----
    {
        sh8 bq[4], bqn[4];
        {
            int n0 = (wv*3)*16 + l15;
            #pragma unroll
            for (int kk = 0; kk < 4; ++kk)
                bq[kk] = *(const sh8*)(wq + n0*C_ + kk*32 + l4*8);
        }
        for (int t = 0; t < 3; ++t) {
            int n0 = (wv*3 + t)*16 + l15;
            if (t < 2) {
                int n1 = n0 + 16;
                #pragma unroll
                for (int kk = 0; kk < 4; ++kk)
                    bqn[kk] = *(const sh8*)(wq + n1*C_ + kk*32 + l4*8);
            }
            int mat = n0 >> 7, c = n0 & 127;
            float bias = qkvb[n0];
            float scl = (mat == 0) ? SCALE_ : 1.f;
            #pragma unroll
            for (int mt4 = 0; mt4 < 4; ++mt4) {
                f32x4 acc = {0.f,0.f,0.f,0.f};
                #pragma unroll
                for (int kk = 0; kk < 4; ++kk) {
                    sh8 av = *(const sh8*)(xsp + (mt4*16 + l15)*136 + kk*32 + l4*8);
                    acc = __builtin_amdgcn_mfma_f32_16x16x32_bf16(av, bq[kk], acc, 0,0,0);
                }
                #pragma unroll
                for (int r = 0; r < 4; ++r) {
                    int m0 = mt4*16 + l4*4 + r;
                    float vc = (acc[r] + bias) * scl;
                    if (mat == 0)      q_s[m0*136 + c] = f2bs(vc);
                    else if (mat == 1) k_s[m0*136 + c] = f2bs(vc);
                    else               vt[c*72 + m0]   = f2bs(vc);
                }
            }
            #pragma unroll
            for (int kk = 0; kk < 4; ++kk) bq[kk] = bqn[kk];
        }
    }
    __syncthreads();

    // ---- phase B: swapped QK^T -> lane-local softmax -> in-register P -> PV ----
    int zq;
    {
        int qt = mt*16 + l15;
        int rt = qt / WS_, ct = qt % WS_;
        int hi = wr*WS_ + rt, wi2 = wc*WS_ + ct;
        zq = (hi < 63 ? 0 : (hi < 67 ? 1 : 2))*3 + (wi2 < 28 ? 0 : (wi2 < 32 ? 1 : 2));
    }
    int zk[4][4];
    #pragma unroll
    for (int nt = 0; nt < 4; ++nt)
        #pragma unroll
        for (int r = 0; r < 4; ++r) {
            int kt = nt*16 + l4*4 + r;
            int rt = kt / WS_, ct = kt % WS_;
            int hj = wr*WS_ + rt, wj = wc*WS_ + ct;
            zk[nt][r] = (hj < 63 ? 0 : (hj < 67 ? 1 : 2))*3 + (wj < 28 ? 0 : (wj < 32 ? 1 : 2));
        }

    const int sl0 = ((l4 & 1) * 2)*16 + l15;   // src lane, j>>2 == 0
    const int sl1 = sl0 + 16;                  // src lane, j>>2 == 1
    const bool hi4 = (l4 >> 1) != 0;           // selects nt = 2ks+1

    f32x4 o_acc[2][2] = {};
    #pragma unroll
    for (int hl = 0; hl < 2; ++hl) {
        const int h = hg*2 + hl;
        // B operand = Q (cols = q tokens), A operand = K (rows = k tokens)
        sh8 qf = *(const sh8*)(q_s + (mt*16 + l15)*136 + h*HD_ + l4*8);
        f32x4 s[4];
        __builtin_amdgcn_s_setprio(1);
        #pragma unroll
        for (int nt = 0; nt < 4; ++nt) {
            sh8 kf = *(const sh8*)(k_s + (nt*16 + l15)*136 + h*HD_ + l4*8);
            f32x4 z = {0.f,0.f,0.f,0.f};
            s[nt] = __builtin_amdgcn_mfma_f32_16x16x32_bf16(kf, qf, z, 0,0,0);
            // s[nt][r] = S[k = nt*16 + l4*4 + r][q = mt*16 + l15]
        }
        __builtin_amdgcn_s_setprio(0);
        // bias (btT[h][k][q], coalesced over l15) + zone mask; q = mt*16 + l15
        #pragma unroll
        for (int nt = 0; nt < 4; ++nt)
            #pragma unroll
            for (int r = 0; r < 4; ++r) {
                float sv = s[nt][r]
                    + bs2f(btT[((size_t)(h*64 + nt*16 + l4*4 + r))*64 + mt*16 + l15]);
                if (zq != zk[nt][r]) sv -= 100.f;
                s[nt][r] = sv;
            }
        // softmax over k (16 lane-local + cross-l4 via 2 shfl)
        float m0 = s[0][0];
        #pragma unroll
        for (int nt = 0; nt < 4; ++nt)
            #pragma unroll
            for (int r = 0; r < 4; ++r) m0 = fmaxf(m0, s[nt][r]);
        m0 = fmaxf(m0, __shfl_xor(m0, 16));
        m0 = fmaxf(m0, __shfl_xor(m0, 32));
        float ls = 0.f;
        #pragma unroll
        for (int nt = 0; nt < 4; ++nt)
            #pragma unroll
            for (int r = 0; r < 4; ++r) {
                float e = __expf(s[nt][r] - m0);
                s[nt][r] = e; ls += e;
            }
        ls += __shfl_xor(ls, 16);
        ls += __shfl_xor(ls, 32);
        float inv = 1.f / ls;
        // pack P pairs (bf16x2) per nt: p01 = (r1,r0), p23 = (r3,r2)
        unsigned p01[4], p23[4];
        #pragma unroll
        for (int nt = 0; nt < 4; ++nt) {
            p01[nt] = pk2(s[nt][0]*inv, s[nt][1]*inv);
            p23[nt] = pk2(s[nt][2]*inv, s[nt][3]*inv);
        }
        // build PV A-fragments in-register: ap[j] = P[q=l15][k=ks*32+l4*8+j]
        // NOTE: all shuffles executed UNCONDITIONALLY (uniform control flow);
        // selecting the variable inside a divergent ternary made ds_bpermute
        // read inactive source lanes -> zeros (the r16/r17 0.208 bug).
        #pragma unroll
        for (int ks = 0; ks < 2; ++ks) {
            unsigned u01_lo = __shfl(p01[2*ks],   sl0);
            unsigned u01_hi = __shfl(p01[2*ks+1], sl0);
            unsigned u23_lo = __shfl(p23[2*ks],   sl0);
            unsigned u23_hi = __shfl(p23[2*ks+1], sl0);
            unsigned v01_lo = __shfl(p01[2*ks],   sl1);
            unsigned v01_hi = __shfl(p01[2*ks+1], sl1);
            unsigned v23_lo = __shfl(p23[2*ks],   sl1);
            unsigned v23_hi = __shfl(p23[2*ks+1], sl1);
            unsigned a01 = hi4 ? u01_hi : u01_lo;
            unsigned a23 = hi4 ? u23_hi : u23_lo;
            unsigned a45 = hi4 ? v01_hi : v01_lo;
            unsigned a67 = hi4 ? v23_hi : v23_lo;
            int w4[4] = {(int)a01, (int)a23, (int)a45, (int)a67};
            sh8 ap; __builtin_memcpy(&ap, w4, 16);
            sh8 bv0 = *(const sh8*)(vt + (h*HD_ + l15)*72      + ks*32 + l4*8);
            sh8 bv1 = *(const sh8*)(vt + (h*HD_ + 16 + l15)*72 + ks*32 + l4*8);
            __builtin_amdgcn_s_setprio(1);
            o_acc[hl][0] = __builtin_amdgcn_mfma_f32_16x16x32_bf16(ap, bv0, o_acc[hl][0], 0,0,0);
            o_acc[hl][1] = __builtin_amdgcn_mfma_f32_16x16x32_bf16(ap, bv1, o_acc[hl][1], 0,0,0);
            __builtin_amdgcn_s_setprio(0);
        }
    }

    __syncthreads();   // k_s reads done -> cat may overlay

    // ---- phase C: cat write -> BARRIER (cross-hg channel reads) -> proj ----
    #pragma unroll
    for (int hl = 0; hl < 2; ++hl)
        #pragma unroll
        for (int nt2 = 0; nt2 < 2; ++nt2)
            #pragma unroll
            for (int r = 0; r < 4; ++r)
                cat[(mt*16 + l4*4 + r)*136 + (hg*2+hl)*HD_ + nt2*16 + l15] = f2bs(o_acc[hl][nt2][r]);
    __syncthreads();   // pa reads ALL 128 channels incl. the other hg-wave's half

    bool pred[4]; size_t tokb[4];
    #pragma unroll
    for (int r = 0; r < 4; ++r) {
        int m = mt*16 + l4*4 + r;
        int rr = m / WS_, cc = m % WS_;
        int hh = (wr*WS_ + rr + SS_) % Hp;
        int ww = (wc*WS_ + cc + SS_) % Wp;
        pred[r] = (m < NTOK_) && (hh < H1_) && (ww < W1_);
        tokb[r] = ((size_t)(b*H1_*W1_ + hh*W1_ + ww))*C_;
    }

    sh8 pa[4];
    #pragma unroll
    for (int kk = 0; kk < 4; ++kk)
        pa[kk] = *(const sh8*)(cat + (mt*16 + l15)*136 + kk*32 + l4*8);

    sh8 bpw[4], bpwn[4];
    #pragma unroll
    for (int kk = 0; kk < 4; ++kk)
        bpw[kk] = *(const sh8*)(wp + (hg*64 + l15)*C_ + kk*32 + l4*8);
    for (int nt = 0; nt < 4; ++nt) {
        int ch = hg*64 + nt*16 + l15;
        if (nt < 3) {
            #pragma unroll
            for (int kk = 0; kk < 4; ++kk)
                bpwn[kk] = *(const sh8*)(wp + (ch+16)*C_ + kk*32 + l4*8);
        }
        f32x4 acc = {0.f,0.f,0.f,0.f};
        #pragma unroll
        for (int kk = 0; kk < 4; ++kk)
            acc = __builtin_amdgcn_mfma_f32_16x16x32_bf16(pa[kk], bpw[kk], acc, 0,0,0);
        float pbv = projb[ch];
        #pragma unroll
        for (int r = 0; r < 4; ++r)
            if (pred[r])
                out[tokb[r] + ch] = acc[r] + pbv;   // attn contribution only; x added in mlp
        #pragma unroll
        for (int kk = 0; kk < 4; ++kk) bpw[kk] = bpwn[kk];
    }
}

// ---- mlp v5: res = x + attn (both coalesced), LN2, fc1/fc2, write-once ----
// LDS: xin f32[64][132] @0 | hv bf16[64][264] @0 (overlay) | outs f32 @0 ;
//      h2 bf16[64][136] @33792 -> total 51200
__global__ __launch_bounds__(512) void mlp_k(
    const float* __restrict__ x,
    float* __restrict__ xio,
    const float* __restrict__ n2g, const float* __restrict__ n2b,
    const float* __restrict__ f1b, const float* __restrict__ f2b,
    const short* __restrict__ w1, const short* __restrict__ w2)
{
    __shared__ char smem[51200];
    float* xin = (float*)smem;               // [64][132]
    short* hv  = (short*)smem;               // [64][264], after xin dies
    float* outs= (float*)smem;               // [64][132], after hv dies
    short* h2  = (short*)(smem + 33792);     // [64][136]

    const int tid = threadIdx.x;
    const int lane = tid & 63, wv = tid >> 6;
    const int l15 = lane & 15, l4 = lane >> 4;
    const int mh = wv & 1, ng = wv >> 1;
    const size_t base = (size_t)blockIdx.x * 64 * C_;

    // stage residual = x + attn (both contiguous full-line reads)
    for (int i = tid; i < 2048; i += 512) {
        float4 vx = ((const float4*)(x + base))[i];
        float4 va = ((const float4*)(xio + base))[i];
        vx.x += va.x; vx.y += va.y; vx.z += va.z; vx.w += va.w;
        int row = i >> 5, col = (i & 31) * 4;
        *(float4*)(xin + row*132 + col) = vx;
    }
    __syncthreads();

    {
        int tok = tid >> 3, sub = tid & 7;
        float vbuf[16];
        float s = 0.f, sq = 0.f;
        #pragma unroll
        for (int c = 0; c < 16; ++c) {
            float v = xin[tok*132 + sub*16 + c];
            vbuf[c] = v; s += v; sq += v*v;
        }
        #pragma unroll
        for (int off = 1; off < 8; off <<= 1) {
            s  += __shfl_xor(s, off);
            sq += __shfl_xor(sq, off);
        }
        float mean = s * (1.f/128.f);
        float var  = sq * (1.f/128.f) - mean*mean;
        float rstd = rsqrtf(var + 1e-5f);
        #pragma unroll
        for (int c = 0; c < 16; ++c) {
            int ch = sub*16 + c;
            h2[tok*136 + ch] = f2bs((vbuf[c] - mean)*rstd*n2g[ch] + n2b[ch]);
        }
    }
    float res[2][2][4];
    #pragma unroll
    for (int mt2 = 0; mt2 < 2; ++mt2)
        #pragma unroll
        for (int nt = 0; nt < 2; ++nt)
            #pragma unroll
            for (int r = 0; r < 4; ++r) {
                int m  = (mh*2 + mt2)*16 + l4*4 + r;
                int ch = ng*32 + nt*16 + l15;
                res[mt2][nt][r] = xin[m*132 + ch];
            }
    __syncthreads();   // xin dead -> hv may overlay

    f32x4 facc[2][2] = {};
    #pragma unroll 1
    for (int chunk = 0; chunk < 2; ++chunk) {
        const int c0 = chunk*256;
        // ---- fc1 + GELU: chunk-local cols ng*64..+63, both m-tiles ----
        {
            sh8 b1[4], b1n[4];
            #pragma unroll
            for (int kk = 0; kk < 4; ++kk)
                b1[kk] = *(const sh8*)(w1 + (size_t)(c0 + ng*64 + l15)*C_ + kk*32 + l4*8);
            for (int t = 0; t < 4; ++t) {
                int n = c0 + ng*64 + t*16 + l15;
                if (t < 3) {
                    #pragma unroll
                    for (int kk = 0; kk < 4; ++kk)
                        b1n[kk] = *(const sh8*)(w1 + (size_t)(n + 16)*C_ + kk*32 + l4*8);
                }
                float bias = f1b[n];
                #pragma unroll
                for (int mt2 = 0; mt2 < 2; ++mt2) {
                    int mrow = (mh*2 + mt2)*16;
                    f32x4 acc = {0.f,0.f,0.f,0.f};
                    #pragma unroll
                    for (int kk = 0; kk < 4; ++kk) {
                        sh8 av = *(const sh8*)(h2 + (mrow + l15)*136 + kk*32 + l4*8);
                        acc = __builtin_amdgcn_mfma_f32_16x16x32_bf16(av, b1[kk], acc, 0,0,0);
                    }
                    #pragma unroll
                    for (int r = 0; r < 4; ++r) {
                        float xv = acc[r] + bias;
                        float g = xv * 0.5f * (1.f + erff(xv * 0.70710678118654752f));
                        hv[(mrow + l4*4 + r)*264 + ng*64 + t*16 + l15] = f2bs(g);
                    }
                }
                #pragma unroll
                for (int kk = 0; kk < 4; ++kk) b1[kk] = b1n[kk];
            }
        }
        __syncthreads();
        // ---- fc2 partial: K = [c0, c0+256), out cols ng*32..+31, both m-tiles ----
        {
            sh8 b2[2], b2n[2];
            #pragma unroll
            for (int nt = 0; nt < 2; ++nt)
                b2[nt] = *(const sh8*)(w2 + (size_t)(ng*32 + nt*16 + l15)*512 + c0 + l4*8);
            for (int ks = 0; ks < 8; ++ks) {
                if (ks < 7) {
                    #pragma unroll
                    for (int nt = 0; nt < 2; ++nt)
                        b2n[nt] = *(const sh8*)(w2 + (size_t)(ng*32 + nt*16 + l15)*512 + c0 + (ks+1)*32 + l4*8);
                }
                #pragma unroll
                for (int mt2 = 0; mt2 < 2; ++mt2) {
                    sh8 av = *(const sh8*)(hv + ((mh*2 + mt2)*16 + l15)*264 + ks*32 + l4*8);
                    facc[mt2][0] = __builtin_amdgcn_mfma_f32_16x16x32_bf16(av, b2[0], facc[mt2][0], 0,0,0);
                    facc[mt2][1] = __builtin_amdgcn_mfma_f32_16x16x32_bf16(av, b2[1], facc[mt2][1], 0,0,0);
                }
                b2[0] = b2n[0]; b2[1] = b2n[1];
            }
        }
        __syncthreads();
    }

    #pragma unroll
    for (int mt2 = 0; mt2 < 2; ++mt2)
        #pragma unroll
        for (int nt = 0; nt < 2; ++nt) {
            int oc = ng*32 + nt*16 + l15;
            float bias = f2b[oc];
            #pragma unroll
            for (int r = 0; r < 4; ++r) {
                int m = (mh*2 + mt2)*16 + l4*4 + r;
                outs[m*132 + oc] = res[mt2][nt][r] + facc[mt2][nt][r] + bias;
            }
        }
    __syncthreads();
    for (int i = tid; i < 2048; i += 512) {
        int row = i >> 5, col = (i & 31) * 4;
        ((float4*)(xio + base))[i] = *(const float4*)(outs + row*132 + col);
    }
}

extern "C" void kernel_launch(void* const* d_in, const int* in_sizes, int n_in,
                              void* d_out, int out_size, void* d_ws, size_t ws_size,
                              hipStream_t stream) {
    const float* x    = (const float*)d_in[0];
    const float* n1g  = (const float*)d_in[1];
    const float* n1b  = (const float*)d_in[2];
    const float* qkvw = (const float*)d_in[3];
    const float* qkvb = (const float*)d_in[4];
    const float* rpb  = (const float*)d_in[5];
    const float* pw   = (const float*)d_in[6];
    const float* pb   = (const float*)d_in[7];
    const float* n2g  = (const float*)d_in[8];
    const float* n2b  = (const float*)d_in[9];
    const float* f1w  = (const float*)d_in[10];
    const float* f1b  = (const float*)d_in[11];
    const float* f2w  = (const float*)d_in[12];
    const float* f2b  = (const float*)d_in[13];

    short* ws = (short*)d_ws;          // bf16 weights + bias table (426 KB)
    const short* wq = ws;
    const short* wp = ws + 49152;
    const short* w1 = ws + 65536;
    const short* w2 = ws + 131072;
    const short* bt = ws + 196608;
    float* xio = (float*)d_out;

    hipLaunchKernelGGL(prep_k, dim3(832), dim3(256), 0, stream, qkvw, pw, f1w, f2w, rpb, ws);
    hipLaunchKernelGGL(win_attn, dim3(B_*NWIN_), dim3(512), 0, stream,
                       x, n1g, n1b, qkvb, bt, pb, wq, wp, xio);
    hipLaunchKernelGGL(mlp_k, dim3(B_*H1_*W1_/64), dim3(512), 0, stream,
                       x, xio, n2g, n2b, f1b, f2b, w1, w2);
}

// Round 19
// 302.983 us; speedup vs baseline: 1.0278x; 1.0278x over previous
//
#include <hip/hip_runtime.h>
#include <hip/hip_bf16.h>

#define B_ 64
#define H1_ 64
#define W1_ 32
#define Hp 70
#define Wp 35
#define C_ 128
#define NH_ 4
#define HD_ 32
#define WS_ 7
#define SS_ 3
#define NWC_ 5
#define NWIN_ 50
#define NTOK_ 49
#define SCALE_ 0.17677669529663687f

typedef __hip_bfloat16 bf16;
typedef __attribute__((ext_vector_type(8))) short sh8;     // 8 bf16 = 4 VGPR
typedef __attribute__((ext_vector_type(4))) float f32x4;   // MFMA acc

__device__ __forceinline__ float bs2f(short s) {
    unsigned int u = ((unsigned int)(unsigned short)s) << 16;
    float f; __builtin_memcpy(&f, &u, 4); return f;
}
__device__ __forceinline__ short f2bs(float f) {
    bf16 h = __float2bfloat16(f);
    return *reinterpret_cast<short*>(&h);
}
__device__ __forceinline__ unsigned pk2(float lo, float hi) {
    return ((unsigned)(unsigned short)f2bs(hi) << 16) | (unsigned)(unsigned short)f2bs(lo);
}

// ---- prep: fp32 weights -> bf16 [N][K] + TRANSPOSED attn-bias table ----
// ws layout (shorts): wq[384][128] @0 ; wp[128][128] @49152 ; w1[512][128] @65536 ;
//                     w2[128][512] @131072 ; btT[4][64 k][64 q] @196608 (ends 212992)
__global__ void prep_k(const float* __restrict__ qkvw, const float* __restrict__ projw,
                       const float* __restrict__ f1w, const float* __restrict__ f2w,
                       const float* __restrict__ rpb,
                       short* __restrict__ ws) {
    int tid = blockIdx.x * 256 + threadIdx.x;          // 832*256 = 212992 total
    if (tid < 49152) {
        int n = tid >> 7, k = tid & 127;               // qkv_w [128][384]
        ws[tid] = f2bs(qkvw[k*384 + n]);
    } else if (tid < 65536) {
        int t = tid - 49152; int n = t >> 7, k = t & 127;   // proj_w [128][128]
        ws[tid] = f2bs(projw[k*128 + n]);
    } else if (tid < 131072) {
        int t = tid - 65536; int n = t >> 7, k = t & 127;   // fc1_w [128][512]
        ws[tid] = f2bs(f1w[k*512 + n]);
    } else if (tid < 196608) {
        int t = tid - 131072; int n = t >> 9, k = t & 511;  // fc2_w [512][128]
        ws[tid] = f2bs(f2w[k*128 + n]);
    } else if (tid < 212992) {
        int t = tid - 196608;                               // btT [4][k][q]
        int h = t >> 12, k = (t >> 6) & 63, q = t & 63;
        float val = -30000.f;                               // padded rows/cols
        if (q < NTOK_ && k < NTOK_) {
            int ri = q / WS_, ci = q % WS_, rj = k / WS_, cj = k % WS_;
            val = rpb[((ri - rj + 6)*13 + (ci - cj + 6))*4 + h];
        }
        ws[tid] = f2bs(val);
    }
}

// ---- win_attn, 8 waves; swapped-QK^T lane-local softmax, in-register P ----
// LDS map (70656 B, 2 blocks/CU):
//   [0,17408)       q_s  bf16[64][136]
//   [17408,34816)   k_s  bf16[64][136]  -> cat (phase C)
//   [34816,53248)   vt   bf16[128][72]  (V transposed: [ch][tok])
//   [53248,70656)   xsp  bf16[64][136]  (phase A only)
__global__ __launch_bounds__(512, 4) void win_attn(
    const float* __restrict__ x,
    const float* __restrict__ n1g, const float* __restrict__ n1b,
    const float* __restrict__ qkvb, const short* __restrict__ btT,
    const float* __restrict__ projb,
    const short* __restrict__ wq, const short* __restrict__ wp,
    float* __restrict__ out)
{
    __shared__ char smem[70656];
    short* q_s = (short*)smem;
    short* k_s = (short*)(smem + 17408);
    short* cat = (short*)(smem + 17408);
    short* vt  = (short*)(smem + 34816);
    short* xsp = (short*)(smem + 53248);

    const int tid = threadIdx.x;
    const int lane = tid & 63, wv = tid >> 6;
    const int l15 = lane & 15, l4 = lane >> 4;
    const int mt = wv & 3, hg = wv >> 2;
    const int bw = blockIdx.x;
    const int b = bw / NWIN_, win = bw % NWIN_;
    const int wr = win / NWC_, wc = win % NWC_;

    // ---- phase A1: gather + LN1, float4; 2 rows/wave/iter ----
    {
        const int c0 = (lane & 31) * 4;
        const float4 g4 = *(const float4*)(n1g + c0);   // iteration-invariant
        const float4 b4 = *(const float4*)(n1b + c0);
        #pragma unroll
        for (int it = 0; it < 4; ++it) {
            int n = it*16 + wv*2 + (lane >> 5);
            int r = n / WS_, cc = n % WS_;
            int h = (wr*WS_ + r + SS_) % Hp;
            int w = (wc*WS_ + cc + SS_) % Wp;
            float4 v = make_float4(0.f, 0.f, 0.f, 0.f);
            if (n < NTOK_ && h < H1_ && w < W1_)
                v = *(const float4*)(x + ((size_t)(b*H1_*W1_ + h*W1_ + w))*C_ + c0);
            float s  = v.x + v.y + v.z + v.w;
            float sq = v.x*v.x + v.y*v.y + v.z*v.z + v.w*v.w;
            #pragma unroll
            for (int off = 1; off < 32; off <<= 1) {
                s  += __shfl_xor(s, off);
                sq += __shfl_xor(sq, off);
            }
            float mean = s * (1.f/128.f);
            float var  = sq * (1.f/128.f) - mean*mean;   // biased var (jnp.var)
            float rstd = rsqrtf(var + 1e-5f);
            short4 o;
            o.x = f2bs((v.x - mean)*rstd*g4.x + b4.x);
            o.y = f2bs((v.y - mean)*rstd*g4.y + b4.y);
            o.z = f2bs((v.z - mean)*rstd*g4.z + b4.z);
            o.w = f2bs((v.w - mean)*rstd*g4.w + b4.w);
            *(short4*)(xsp + n*136 + c0) = o;
        }
    }
    __syncthreads();

    // ---- phase A2: qkv, wave = 3 n-tiles x 4 m-tiles x K=128 ----
    {
        sh8 bq[4], bqn[4];
        {
            int n0 = (wv*3)*16 + l15;
            #pragma unroll
            for (int kk = 0; kk < 4; ++kk)
                bq[kk] = *(const sh8*)(wq + n0*C_ + kk*32 + l4*8);
        }
        for (int t = 0; t < 3; ++t) {
            int n0 = (wv*3 + t)*16 + l15;
            if (t < 2) {
                int n1 = n0 + 16;
                #pragma unroll
                for (int kk = 0; kk < 4; ++kk)
                    bqn[kk] = *(const sh8*)(wq + n1*C_ + kk*32 + l4*8);
            }
            int mat = n0 >> 7, c = n0 & 127;
            float bias = qkvb[n0];
            float scl = (mat == 0) ? SCALE_ : 1.f;
            #pragma unroll
            for (int mt4 = 0; mt4 < 4; ++mt4) {
                f32x4 acc = {0.f,0.f,0.f,0.f};
                #pragma unroll
                for (int kk = 0; kk < 4; ++kk) {
                    sh8 av = *(const sh8*)(xsp + (mt4*16 + l15)*136 + kk*32 + l4*8);
                    acc = __builtin_amdgcn_mfma_f32_16x16x32_bf16(av, bq[kk], acc, 0,0,0);
                }
                int m00 = mt4*16 + l4*4;
                short4 o;
                o.x = f2bs((acc[0] + bias) * scl);
                o.y = f2bs((acc[1] + bias) * scl);
                o.z = f2bs((acc[2] + bias) * scl);
                o.w = f2bs((acc[3] + bias) * scl);
                if (mat == 0) {
                    q_s[(m00+0)*136 + c] = o.x; q_s[(m00+1)*136 + c] = o.y;
                    q_s[(m00+2)*136 + c] = o.z; q_s[(m00+3)*136 + c] = o.w;
                } else if (mat == 1) {
                    k_s[(m00+0)*136 + c] = o.x; k_s[(m00+1)*136 + c] = o.y;
                    k_s[(m00+2)*136 + c] = o.z; k_s[(m00+3)*136 + c] = o.w;
                } else {
                    *(short4*)(vt + c*72 + m00) = o;    // rows consecutive: 1 store
                }
            }
            #pragma unroll
            for (int kk = 0; kk < 4; ++kk) bq[kk] = bqn[kk];
        }
    }
    __syncthreads();

    // ---- phase B: swapped QK^T -> lane-local softmax -> in-register P -> PV ----
    int zq;
    {
        int qt = mt*16 + l15;
        int rt = qt / WS_, ct = qt % WS_;
        int hi = wr*WS_ + rt, wi2 = wc*WS_ + ct;
        zq = (hi < 63 ? 0 : (hi < 67 ? 1 : 2))*3 + (wi2 < 28 ? 0 : (wi2 < 32 ? 1 : 2));
    }
    // preload bias for BOTH heads + fold zone mask (head-independent) into it;
    // issued before the MFMAs so global latency overlaps compute
    float btv[2][4][4];
    #pragma unroll
    for (int nt = 0; nt < 4; ++nt)
        #pragma unroll
        for (int r = 0; r < 4; ++r) {
            int kt = nt*16 + l4*4 + r;
            int rt = kt / WS_, ct = kt % WS_;
            int hj = wr*WS_ + rt, wj = wc*WS_ + ct;
            int zk = (hj < 63 ? 0 : (hj < 67 ? 1 : 2))*3 + (wj < 28 ? 0 : (wj < 32 ? 1 : 2));
            float zm = (zq != zk) ? -100.f : 0.f;
            btv[0][nt][r] = bs2f(btT[((size_t)((hg*2+0)*64 + kt))*64 + mt*16 + l15]) + zm;
            btv[1][nt][r] = bs2f(btT[((size_t)((hg*2+1)*64 + kt))*64 + mt*16 + l15]) + zm;
        }

    const int sl0 = ((l4 & 1) * 2)*16 + l15;   // src lane, j>>2 == 0
    const int sl1 = sl0 + 16;                  // src lane, j>>2 == 1
    const bool hi4 = (l4 >> 1) != 0;           // selects nt = 2ks+1

    f32x4 o_acc[2][2] = {};
    #pragma unroll
    for (int hl = 0; hl < 2; ++hl) {
        const int h = hg*2 + hl;
        // B operand = Q (cols = q tokens), A operand = K (rows = k tokens)
        sh8 qf = *(const sh8*)(q_s + (mt*16 + l15)*136 + h*HD_ + l4*8);
        f32x4 s[4];
        __builtin_amdgcn_s_setprio(1);
        #pragma unroll
        for (int nt = 0; nt < 4; ++nt) {
            sh8 kf = *(const sh8*)(k_s + (nt*16 + l15)*136 + h*HD_ + l4*8);
            f32x4 z = {0.f,0.f,0.f,0.f};
            s[nt] = __builtin_amdgcn_mfma_f32_16x16x32_bf16(kf, qf, z, 0,0,0);
            // s[nt][r] = S[k = nt*16 + l4*4 + r][q = mt*16 + l15]
        }
        __builtin_amdgcn_s_setprio(0);
        #pragma unroll
        for (int nt = 0; nt < 4; ++nt)
            #pragma unroll
            for (int r = 0; r < 4; ++r)
                s[nt][r] += btv[hl][nt][r];
        // softmax over k (16 lane-local + cross-l4 via 2 shfl)
        float m0 = s[0][0];
        #pragma unroll
        for (int nt = 0; nt < 4; ++nt)
            #pragma unroll
            for (int r = 0; r < 4; ++r) m0 = fmaxf(m0, s[nt][r]);
        m0 = fmaxf(m0, __shfl_xor(m0, 16));
        m0 = fmaxf(m0, __shfl_xor(m0, 32));
        float ls = 0.f;
        #pragma unroll
        for (int nt = 0; nt < 4; ++nt)
            #pragma unroll
            for (int r = 0; r < 4; ++r) {
                float e = __expf(s[nt][r] - m0);
                s[nt][r] = e; ls += e;
            }
        ls += __shfl_xor(ls, 16);
        ls += __shfl_xor(ls, 32);
        float inv = 1.f / ls;
        // pack P pairs (bf16x2) per nt: p01 = (r1,r0), p23 = (r3,r2)
        unsigned p01[4], p23[4];
        #pragma unroll
        for (int nt = 0; nt < 4; ++nt) {
            p01[nt] = pk2(s[nt][0]*inv, s[nt][1]*inv);
            p23[nt] = pk2(s[nt][2]*inv, s[nt][3]*inv);
        }
        // build PV A-fragments in-register: ap[j] = P[q=l15][k=ks*32+l4*8+j]
        // shuffles executed UNCONDITIONALLY (uniform control flow), select after
        #pragma unroll
        for (int ks = 0; ks < 2; ++ks) {
            unsigned u01_lo = __shfl(p01[2*ks],   sl0);
            unsigned u01_hi = __shfl(p01[2*ks+1], sl0);
            unsigned u23_lo = __shfl(p23[2*ks],   sl0);
            unsigned u23_hi = __shfl(p23[2*ks+1], sl0);
            unsigned v01_lo = __shfl(p01[2*ks],   sl1);
            unsigned v01_hi = __shfl(p01[2*ks+1], sl1);
            unsigned v23_lo = __shfl(p23[2*ks],   sl1);
            unsigned v23_hi = __shfl(p23[2*ks+1], sl1);
            unsigned a01 = hi4 ? u01_hi : u01_lo;
            unsigned a23 = hi4 ? u23_hi : u23_lo;
            unsigned a45 = hi4 ? v01_hi : v01_lo;
            unsigned a67 = hi4 ? v23_hi : v23_lo;
            int w4[4] = {(int)a01, (int)a23, (int)a45, (int)a67};
            sh8 ap; __builtin_memcpy(&ap, w4, 16);
            sh8 bv0 = *(const sh8*)(vt + (h*HD_ + l15)*72      + ks*32 + l4*8);
            sh8 bv1 = *(const sh8*)(vt + (h*HD_ + 16 + l15)*72 + ks*32 + l4*8);
            __builtin_amdgcn_s_setprio(1);
            o_acc[hl][0] = __builtin_amdgcn_mfma_f32_16x16x32_bf16(ap, bv0, o_acc[hl][0], 0,0,0);
            o_acc[hl][1] = __builtin_amdgcn_mfma_f32_16x16x32_bf16(ap, bv1, o_acc[hl][1], 0,0,0);
            __builtin_amdgcn_s_setprio(0);
        }
    }

    __syncthreads();   // k_s reads done -> cat may overlay

    // ---- phase C: cat write -> BARRIER (cross-hg channel reads) -> proj ----
    #pragma unroll
    for (int hl = 0; hl < 2; ++hl)
        #pragma unroll
        for (int nt2 = 0; nt2 < 2; ++nt2)
            #pragma unroll
            for (int r = 0; r < 4; ++r)
                cat[(mt*16 + l4*4 + r)*136 + (hg*2+hl)*HD_ + nt2*16 + l15] = f2bs(o_acc[hl][nt2][r]);
    __syncthreads();   // pa reads ALL 128 channels incl. the other hg-wave's half

    bool pred[4]; size_t tokb[4];
    #pragma unroll
    for (int r = 0; r < 4; ++r) {
        int m = mt*16 + l4*4 + r;
        int rr = m / WS_, cc = m % WS_;
        int hh = (wr*WS_ + rr + SS_) % Hp;
        int ww = (wc*WS_ + cc + SS_) % Wp;
        pred[r] = (m < NTOK_) && (hh < H1_) && (ww < W1_);
        tokb[r] = ((size_t)(b*H1_*W1_ + hh*W1_ + ww))*C_;
    }

    sh8 pa[4];
    #pragma unroll
    for (int kk = 0; kk < 4; ++kk)
        pa[kk] = *(const sh8*)(cat + (mt*16 + l15)*136 + kk*32 + l4*8);

    sh8 bpw[4], bpwn[4];
    #pragma unroll
    for (int kk = 0; kk < 4; ++kk)
        bpw[kk] = *(const sh8*)(wp + (hg*64 + l15)*C_ + kk*32 + l4*8);
    for (int nt = 0; nt < 4; ++nt) {
        int ch = hg*64 + nt*16 + l15;
        if (nt < 3) {
            #pragma unroll
            for (int kk = 0; kk < 4; ++kk)
                bpwn[kk] = *(const sh8*)(wp + (ch+16)*C_ + kk*32 + l4*8);
        }
        f32x4 acc = {0.f,0.f,0.f,0.f};
        #pragma unroll
        for (int kk = 0; kk < 4; ++kk)
            acc = __builtin_amdgcn_mfma_f32_16x16x32_bf16(pa[kk], bpw[kk], acc, 0,0,0);
        float pbv = projb[ch];
        #pragma unroll
        for (int r = 0; r < 4; ++r)
            if (pred[r])
                out[tokb[r] + ch] = acc[r] + pbv;   // attn contribution only; x added in mlp
        #pragma unroll
        for (int kk = 0; kk < 4; ++kk) bpw[kk] = bpwn[kk];
    }
}

// ---- mlp v5: res = x + attn (both coalesced), LN2, fc1/fc2, write-once ----
// LDS: xin f32[64][132] @0 | hv bf16[64][264] @0 (overlay) | outs f32 @0 ;
//      h2 bf16[64][136] @33792 -> total 51200
__global__ __launch_bounds__(512) void mlp_k(
    const float* __restrict__ x,
    float* __restrict__ xio,
    const float* __restrict__ n2g, const float* __restrict__ n2b,
    const float* __restrict__ f1b, const float* __restrict__ f2b,
    const short* __restrict__ w1, const short* __restrict__ w2)
{
    __shared__ char smem[51200];
    float* xin = (float*)smem;               // [64][132]
    short* hv  = (short*)smem;               // [64][264], after xin dies
    float* outs= (float*)smem;               // [64][132], after hv dies
    short* h2  = (short*)(smem + 33792);     // [64][136]

    const int tid = threadIdx.x;
    const int lane = tid & 63, wv = tid >> 6;
    const int l15 = lane & 15, l4 = lane >> 4;
    const int mh = wv & 1, ng = wv >> 1;
    const size_t base = (size_t)blockIdx.x * 64 * C_;

    // stage residual = x + attn (both contiguous full-line reads)
    for (int i = tid; i < 2048; i += 512) {
        float4 vx = ((const float4*)(x + base))[i];
        float4 va = ((const float4*)(xio + base))[i];
        vx.x += va.x; vx.y += va.y; vx.z += va.z; vx.w += va.w;
        int row = i >> 5, col = (i & 31) * 4;
        *(float4*)(xin + row*132 + col) = vx;
    }
    __syncthreads();

    {
        int tok = tid >> 3, sub = tid & 7;
        float vbuf[16];
        float s = 0.f, sq = 0.f;
        #pragma unroll
        for (int c = 0; c < 16; ++c) {
            float v = xin[tok*132 + sub*16 + c];
            vbuf[c] = v; s += v; sq += v*v;
        }
        #pragma unroll
        for (int off = 1; off < 8; off <<= 1) {
            s  += __shfl_xor(s, off);
            sq += __shfl_xor(sq, off);
        }
        float mean = s * (1.f/128.f);
        float var  = sq * (1.f/128.f) - mean*mean;
        float rstd = rsqrtf(var + 1e-5f);
        #pragma unroll
        for (int c = 0; c < 16; ++c) {
            int ch = sub*16 + c;
            h2[tok*136 + ch] = f2bs((vbuf[c] - mean)*rstd*n2g[ch] + n2b[ch]);
        }
    }
    float res[2][2][4];
    #pragma unroll
    for (int mt2 = 0; mt2 < 2; ++mt2)
        #pragma unroll
        for (int nt = 0; nt < 2; ++nt)
            #pragma unroll
            for (int r = 0; r < 4; ++r) {
                int m  = (mh*2 + mt2)*16 + l4*4 + r;
                int ch = ng*32 + nt*16 + l15;
                res[mt2][nt][r] = xin[m*132 + ch];
            }
    __syncthreads();   // xin dead -> hv may overlay

    f32x4 facc[2][2] = {};
    #pragma unroll 1
    for (int chunk = 0; chunk < 2; ++chunk) {
        const int c0 = chunk*256;
        // ---- fc1 + GELU: chunk-local cols ng*64..+63, both m-tiles ----
        {
            sh8 b1[4], b1n[4];
            #pragma unroll
            for (int kk = 0; kk < 4; ++kk)
                b1[kk] = *(const sh8*)(w1 + (size_t)(c0 + ng*64 + l15)*C_ + kk*32 + l4*8);
            for (int t = 0; t < 4; ++t) {
                int n = c0 + ng*64 + t*16 + l15;
                if (t < 3) {
                    #pragma unroll
                    for (int kk = 0; kk < 4; ++kk)
                        b1n[kk] = *(const sh8*)(w1 + (size_t)(n + 16)*C_ + kk*32 + l4*8);
                }
                float bias = f1b[n];
                #pragma unroll
                for (int mt2 = 0; mt2 < 2; ++mt2) {
                    int mrow = (mh*2 + mt2)*16;
                    f32x4 acc = {0.f,0.f,0.f,0.f};
                    #pragma unroll
                    for (int kk = 0; kk < 4; ++kk) {
                        sh8 av = *(const sh8*)(h2 + (mrow + l15)*136 + kk*32 + l4*8);
                        acc = __builtin_amdgcn_mfma_f32_16x16x32_bf16(av, b1[kk], acc, 0,0,0);
                    }
                    #pragma unroll
                    for (int r = 0; r < 4; ++r) {
                        float xv = acc[r] + bias;
                        float g = xv * 0.5f * (1.f + erff(xv * 0.70710678118654752f));
                        hv[(mrow + l4*4 + r)*264 + ng*64 + t*16 + l15] = f2bs(g);
                    }
                }
                #pragma unroll
                for (int kk = 0; kk < 4; ++kk) b1[kk] = b1n[kk];
            }
        }
        __syncthreads();
        // ---- fc2 partial: K = [c0, c0+256), out cols ng*32..+31, both m-tiles ----
        {
            sh8 b2[2], b2n[2];
            #pragma unroll
            for (int nt = 0; nt < 2; ++nt)
                b2[nt] = *(const sh8*)(w2 + (size_t)(ng*32 + nt*16 + l15)*512 + c0 + l4*8);
            for (int ks = 0; ks < 8; ++ks) {
                if (ks < 7) {
                    #pragma unroll
                    for (int nt = 0; nt < 2; ++nt)
                        b2n[nt] = *(const sh8*)(w2 + (size_t)(ng*32 + nt*16 + l15)*512 + c0 + (ks+1)*32 + l4*8);
                }
                #pragma unroll
                for (int mt2 = 0; mt2 < 2; ++mt2) {
                    sh8 av = *(const sh8*)(hv + ((mh*2 + mt2)*16 + l15)*264 + ks*32 + l4*8);
                    facc[mt2][0] = __builtin_amdgcn_mfma_f32_16x16x32_bf16(av, b2[0], facc[mt2][0], 0,0,0);
                    facc[mt2][1] = __builtin_amdgcn_mfma_f32_16x16x32_bf16(av, b2[1], facc[mt2][1], 0,0,0);
                }
                b2[0] = b2n[0]; b2[1] = b2n[1];
            }
        }
        __syncthreads();
    }

    #pragma unroll
    for (int mt2 = 0; mt2 < 2; ++mt2)
        #pragma unroll
        for (int nt = 0; nt < 2; ++nt) {
            int oc = ng*32 + nt*16 + l15;
            float bias = f2b[oc];
            #pragma unroll
            for (int r = 0; r < 4; ++r) {
                int m = (mh*2 + mt2)*16 + l4*4 + r;
                outs[m*132 + oc] = res[mt2][nt][r] + facc[mt2][nt][r] + bias;
            }
        }
    __syncthreads();
    for (int i = tid; i < 2048; i += 512) {
        int row = i >> 5, col = (i & 31) * 4;
        ((float4*)(xio + base))[i] = *(const float4*)(outs + row*132 + col);
    }
}

extern "C" void kernel_launch(void* const* d_in, const int* in_sizes, int n_in,
                              void* d_out, int out_size, void* d_ws, size_t ws_size,
                              hipStream_t stream) {
    const float* x    = (const float*)d_in[0];
    const float* n1g  = (const float*)d_in[1];
    const float* n1b  = (const float*)d_in[2];
    const float* qkvw = (const float*)d_in[3];
    const float* qkvb = (const float*)d_in[4];
    const float* rpb  = (const float*)d_in[5];
    const float* pw   = (const float*)d_in[6];
    const float* pb   = (const float*)d_in[7];
    const float* n2g  = (const float*)d_in[8];
    const float* n2b  = (const float*)d_in[9];
    const float* f1w  = (const float*)d_in[10];
    const float* f1b  = (const float*)d_in[11];
    const float* f2w  = (const float*)d_in[12];
    const float* f2b  = (const float*)d_in[13];

    short* ws = (short*)d_ws;          // bf16 weights + bias table (426 KB)
    const short* wq = ws;
    const short* wp = ws + 49152;
    const short* w1 = ws + 65536;
    const short* w2 = ws + 131072;
    const short* bt = ws + 196608;
    float* xio = (float*)d_out;

    hipLaunchKernelGGL(prep_k, dim3(832), dim3(256), 0, stream, qkvw, pw, f1w, f2w, rpb, ws);
    hipLaunchKernelGGL(win_attn, dim3(B_*NWIN_), dim3(512), 0, stream,
                       x, n1g, n1b, qkvb, bt, pb, wq, wp, xio);
    hipLaunchKernelGGL(mlp_k, dim3(B_*H1_*W1_/64), dim3(512), 0, stream,
                       x, xio, n2g, n2b, f1b, f2b, w1, w2);
}

// Round 20
// 301.875 us; speedup vs baseline: 1.0316x; 1.0037x over previous
//
#include <hip/hip_runtime.h>
#include <hip/hip_bf16.h>

#define B_ 64
#define H1_ 64
#define W1_ 32
#define Hp 70
#define Wp 35
#define C_ 128
#define NH_ 4
#define HD_ 32
#define WS_ 7
#define SS_ 3
#define NWC_ 5
#define NWIN_ 50
#define NTOK_ 49
#define SCALE_ 0.17677669529663687f

typedef __hip_bfloat16 bf16;
typedef __attribute__((ext_vector_type(8))) short sh8;     // 8 bf16 = 4 VGPR
typedef __attribute__((ext_vector_type(4))) float f32x4;   // MFMA acc

__device__ __forceinline__ float bs2f(short s) {
    unsigned int u = ((unsigned int)(unsigned short)s) << 16;
    float f; __builtin_memcpy(&f, &u, 4); return f;
}
__device__ __forceinline__ short f2bs(float f) {
    bf16 h = __float2bfloat16(f);
    return *reinterpret_cast<short*>(&h);
}
__device__ __forceinline__ unsigned pk2(float lo, float hi) {
    return ((unsigned)(unsigned short)f2bs(hi) << 16) | (unsigned)(unsigned short)f2bs(lo);
}

// ---- prep: fp32 weights -> bf16 [N][K] + TRANSPOSED attn-bias table ----
// ws layout (shorts): wq[384][128] @0 ; wp[128][128] @49152 ; w1[512][128] @65536 ;
//                     w2[128][512] @131072 ; btT[4][64 k][64 q] @196608 (ends 212992)
__global__ void prep_k(const float* __restrict__ qkvw, const float* __restrict__ projw,
                       const float* __restrict__ f1w, const float* __restrict__ f2w,
                       const float* __restrict__ rpb,
                       short* __restrict__ ws) {
    int tid = blockIdx.x * 256 + threadIdx.x;          // 832*256 = 212992 total
    if (tid < 49152) {
        int n = tid >> 7, k = tid & 127;               // qkv_w [128][384]
        ws[tid] = f2bs(qkvw[k*384 + n]);
    } else if (tid < 65536) {
        int t = tid - 49152; int n = t >> 7, k = t & 127;   // proj_w [128][128]
        ws[tid] = f2bs(projw[k*128 + n]);
    } else if (tid < 131072) {
        int t = tid - 65536; int n = t >> 7, k = t & 127;   // fc1_w [128][512]
        ws[tid] = f2bs(f1w[k*512 + n]);
    } else if (tid < 196608) {
        int t = tid - 131072; int n = t >> 9, k = t & 511;  // fc2_w [512][128]
        ws[tid] = f2bs(f2w[k*128 + n]);
    } else if (tid < 212992) {
        int t = tid - 196608;                               // btT [4][k][q]
        int h = t >> 12, k = (t >> 6) & 63, q = t & 63;
        float val = -30000.f;                               // padded rows/cols
        if (q < NTOK_ && k < NTOK_) {
            int ri = q / WS_, ci = q % WS_, rj = k / WS_, cj = k % WS_;
            val = rpb[((ri - rj + 6)*13 + (ci - cj + 6))*4 + h];
        }
        ws[tid] = f2bs(val);
    }
}

// ---- win_attn, 8 waves; swapped-QK^T lane-local softmax, in-register P ----
// (byte-identical to r19)
// LDS map (70656 B, 2 blocks/CU):
//   [0,17408)       q_s  bf16[64][136]
//   [17408,34816)   k_s  bf16[64][136]  -> cat (phase C)
//   [34816,53248)   vt   bf16[128][72]  (V transposed: [ch][tok])
//   [53248,70656)   xsp  bf16[64][136]  (phase A only)
__global__ __launch_bounds__(512, 4) void win_attn(
    const float* __restrict__ x,
    const float* __restrict__ n1g, const float* __restrict__ n1b,
    const float* __restrict__ qkvb, const short* __restrict__ btT,
    const float* __restrict__ projb,
    const short* __restrict__ wq, const short* __restrict__ wp,
    float* __restrict__ out)
{
    __shared__ char smem[70656];
    short* q_s = (short*)smem;
    short* k_s = (short*)(smem + 17408);
    short* cat = (short*)(smem + 17408);
    short* vt  = (short*)(smem + 34816);
    short* xsp = (short*)(smem + 53248);

    const int tid = threadIdx.x;
    const int lane = tid & 63, wv = tid >> 6;
    const int l15 = lane & 15, l4 = lane >> 4;
    const int mt = wv & 3, hg = wv >> 2;
    const int bw = blockIdx.x;
    const int b = bw / NWIN_, win = bw % NWIN_;
    const int wr = win / NWC_, wc = win % NWC_;

    // ---- phase A1: gather + LN1, float4; 2 rows/wave/iter ----
    {
        const int c0 = (lane & 31) * 4;
        const float4 g4 = *(const float4*)(n1g + c0);   // iteration-invariant
        const float4 b4 = *(const float4*)(n1b + c0);
        #pragma unroll
        for (int it = 0; it < 4; ++it) {
            int n = it*16 + wv*2 + (lane >> 5);
            int r = n / WS_, cc = n % WS_;
            int h = (wr*WS_ + r + SS_) % Hp;
            int w = (wc*WS_ + cc + SS_) % Wp;
            float4 v = make_float4(0.f, 0.f, 0.f, 0.f);
            if (n < NTOK_ && h < H1_ && w < W1_)
                v = *(const float4*)(x + ((size_t)(b*H1_*W1_ + h*W1_ + w))*C_ + c0);
            float s  = v.x + v.y + v.z + v.w;
            float sq = v.x*v.x + v.y*v.y + v.z*v.z + v.w*v.w;
            #pragma unroll
            for (int off = 1; off < 32; off <<= 1) {
                s  += __shfl_xor(s, off);
                sq += __shfl_xor(sq, off);
            }
            float mean = s * (1.f/128.f);
            float var  = sq * (1.f/128.f) - mean*mean;   // biased var (jnp.var)
            float rstd = rsqrtf(var + 1e-5f);
            short4 o;
            o.x = f2bs((v.x - mean)*rstd*g4.x + b4.x);
            o.y = f2bs((v.y - mean)*rstd*g4.y + b4.y);
            o.z = f2bs((v.z - mean)*rstd*g4.z + b4.z);
            o.w = f2bs((v.w - mean)*rstd*g4.w + b4.w);
            *(short4*)(xsp + n*136 + c0) = o;
        }
    }
    __syncthreads();

    // ---- phase A2: qkv, wave = 3 n-tiles x 4 m-tiles x K=128 ----
    {
        sh8 bq[4], bqn[4];
        {
            int n0 = (wv*3)*16 + l15;
            #pragma unroll
            for (int kk = 0; kk < 4; ++kk)
                bq[kk] = *(const sh8*)(wq + n0*C_ + kk*32 + l4*8);
        }
        for (int t = 0; t < 3; ++t) {
            int n0 = (wv*3 + t)*16 + l15;
            if (t < 2) {
                int n1 = n0 + 16;
                #pragma unroll
                for (int kk = 0; kk < 4; ++kk)
                    bqn[kk] = *(const sh8*)(wq + n1*C_ + kk*32 + l4*8);
            }
            int mat = n0 >> 7, c = n0 & 127;
            float bias = qkvb[n0];
            float scl = (mat == 0) ? SCALE_ : 1.f;
            #pragma unroll
            for (int mt4 = 0; mt4 < 4; ++mt4) {
                f32x4 acc = {0.f,0.f,0.f,0.f};
                #pragma unroll
                for (int kk = 0; kk < 4; ++kk) {
                    sh8 av = *(const sh8*)(xsp + (mt4*16 + l15)*136 + kk*32 + l4*8);
                    acc = __builtin_amdgcn_mfma_f32_16x16x32_bf16(av, bq[kk], acc, 0,0,0);
                }
                int m00 = mt4*16 + l4*4;
                short4 o;
                o.x = f2bs((acc[0] + bias) * scl);
                o.y = f2bs((acc[1] + bias) * scl);
                o.z = f2bs((acc[2] + bias) * scl);
                o.w = f2bs((acc[3] + bias) * scl);
                if (mat == 0) {
                    q_s[(m00+0)*136 + c] = o.x; q_s[(m00+1)*136 + c] = o.y;
                    q_s[(m00+2)*136 + c] = o.z; q_s[(m00+3)*136 + c] = o.w;
                } else if (mat == 1) {
                    k_s[(m00+0)*136 + c] = o.x; k_s[(m00+1)*136 + c] = o.y;
                    k_s[(m00+2)*136 + c] = o.z; k_s[(m00+3)*136 + c] = o.w;
                } else {
                    *(short4*)(vt + c*72 + m00) = o;    // rows consecutive: 1 store
                }
            }
            #pragma unroll
            for (int kk = 0; kk < 4; ++kk) bq[kk] = bqn[kk];
        }
    }
    __syncthreads();

    // ---- phase B: swapped QK^T -> lane-local softmax -> in-register P -> PV ----
    int zq;
    {
        int qt = mt*16 + l15;
        int rt = qt / WS_, ct = qt % WS_;
        int hi = wr*WS_ + rt, wi2 = wc*WS_ + ct;
        zq = (hi < 63 ? 0 : (hi < 67 ? 1 : 2))*3 + (wi2 < 28 ? 0 : (wi2 < 32 ? 1 : 2));
    }
    // preload bias for BOTH heads + fold zone mask (head-independent) into it
    float btv[2][4][4];
    #pragma unroll
    for (int nt = 0; nt < 4; ++nt)
        #pragma unroll
        for (int r = 0; r < 4; ++r) {
            int kt = nt*16 + l4*4 + r;
            int rt = kt / WS_, ct = kt % WS_;
            int hj = wr*WS_ + rt, wj = wc*WS_ + ct;
            int zk = (hj < 63 ? 0 : (hj < 67 ? 1 : 2))*3 + (wj < 28 ? 0 : (wj < 32 ? 1 : 2));
            float zm = (zq != zk) ? -100.f : 0.f;
            btv[0][nt][r] = bs2f(btT[((size_t)((hg*2+0)*64 + kt))*64 + mt*16 + l15]) + zm;
            btv[1][nt][r] = bs2f(btT[((size_t)((hg*2+1)*64 + kt))*64 + mt*16 + l15]) + zm;
        }

    const int sl0 = ((l4 & 1) * 2)*16 + l15;   // src lane, j>>2 == 0
    const int sl1 = sl0 + 16;                  // src lane, j>>2 == 1
    const bool hi4 = (l4 >> 1) != 0;           // selects nt = 2ks+1

    f32x4 o_acc[2][2] = {};
    #pragma unroll
    for (int hl = 0; hl < 2; ++hl) {
        const int h = hg*2 + hl;
        sh8 qf = *(const sh8*)(q_s + (mt*16 + l15)*136 + h*HD_ + l4*8);
        f32x4 s[4];
        __builtin_amdgcn_s_setprio(1);
        #pragma unroll
        for (int nt = 0; nt < 4; ++nt) {
            sh8 kf = *(const sh8*)(k_s + (nt*16 + l15)*136 + h*HD_ + l4*8);
            f32x4 z = {0.f,0.f,0.f,0.f};
            s[nt] = __builtin_amdgcn_mfma_f32_16x16x32_bf16(kf, qf, z, 0,0,0);
        }
        __builtin_amdgcn_s_setprio(0);
        #pragma unroll
        for (int nt = 0; nt < 4; ++nt)
            #pragma unroll
            for (int r = 0; r < 4; ++r)
                s[nt][r] += btv[hl][nt][r];
        float m0 = s[0][0];
        #pragma unroll
        for (int nt = 0; nt < 4; ++nt)
            #pragma unroll
            for (int r = 0; r < 4; ++r) m0 = fmaxf(m0, s[nt][r]);
        m0 = fmaxf(m0, __shfl_xor(m0, 16));
        m0 = fmaxf(m0, __shfl_xor(m0, 32));
        float ls = 0.f;
        #pragma unroll
        for (int nt = 0; nt < 4; ++nt)
            #pragma unroll
            for (int r = 0; r < 4; ++r) {
                float e = __expf(s[nt][r] - m0);
                s[nt][r] = e; ls += e;
            }
        ls += __shfl_xor(ls, 16);
        ls += __shfl_xor(ls, 32);
        float inv = 1.f / ls;
        unsigned p01[4], p23[4];
        #pragma unroll
        for (int nt = 0; nt < 4; ++nt) {
            p01[nt] = pk2(s[nt][0]*inv, s[nt][1]*inv);
            p23[nt] = pk2(s[nt][2]*inv, s[nt][3]*inv);
        }
        #pragma unroll
        for (int ks = 0; ks < 2; ++ks) {
            unsigned u01_lo = __shfl(p01[2*ks],   sl0);
            unsigned u01_hi = __shfl(p01[2*ks+1], sl0);
            unsigned u23_lo = __shfl(p23[2*ks],   sl0);
            unsigned u23_hi = __shfl(p23[2*ks+1], sl0);
            unsigned v01_lo = __shfl(p01[2*ks],   sl1);
            unsigned v01_hi = __shfl(p01[2*ks+1], sl1);
            unsigned v23_lo = __shfl(p23[2*ks],   sl1);
            unsigned v23_hi = __shfl(p23[2*ks+1], sl1);
            unsigned a01 = hi4 ? u01_hi : u01_lo;
            unsigned a23 = hi4 ? u23_hi : u23_lo;
            unsigned a45 = hi4 ? v01_hi : v01_lo;
            unsigned a67 = hi4 ? v23_hi : v23_lo;
            int w4[4] = {(int)a01, (int)a23, (int)a45, (int)a67};
            sh8 ap; __builtin_memcpy(&ap, w4, 16);
            sh8 bv0 = *(const sh8*)(vt + (h*HD_ + l15)*72      + ks*32 + l4*8);
            sh8 bv1 = *(const sh8*)(vt + (h*HD_ + 16 + l15)*72 + ks*32 + l4*8);
            __builtin_amdgcn_s_setprio(1);
            o_acc[hl][0] = __builtin_amdgcn_mfma_f32_16x16x32_bf16(ap, bv0, o_acc[hl][0], 0,0,0);
            o_acc[hl][1] = __builtin_amdgcn_mfma_f32_16x16x32_bf16(ap, bv1, o_acc[hl][1], 0,0,0);
            __builtin_amdgcn_s_setprio(0);
        }
    }

    __syncthreads();   // k_s reads done -> cat may overlay

    // ---- phase C: cat write -> BARRIER (cross-hg channel reads) -> proj ----
    #pragma unroll
    for (int hl = 0; hl < 2; ++hl)
        #pragma unroll
        for (int nt2 = 0; nt2 < 2; ++nt2)
            #pragma unroll
            for (int r = 0; r < 4; ++r)
                cat[(mt*16 + l4*4 + r)*136 + (hg*2+hl)*HD_ + nt2*16 + l15] = f2bs(o_acc[hl][nt2][r]);
    __syncthreads();

    bool pred[4]; size_t tokb[4];
    #pragma unroll
    for (int r = 0; r < 4; ++r) {
        int m = mt*16 + l4*4 + r;
        int rr = m / WS_, cc = m % WS_;
        int hh = (wr*WS_ + rr + SS_) % Hp;
        int ww = (wc*WS_ + cc + SS_) % Wp;
        pred[r] = (m < NTOK_) && (hh < H1_) && (ww < W1_);
        tokb[r] = ((size_t)(b*H1_*W1_ + hh*W1_ + ww))*C_;
    }

    sh8 pa[4];
    #pragma unroll
    for (int kk = 0; kk < 4; ++kk)
        pa[kk] = *(const sh8*)(cat + (mt*16 + l15)*136 + kk*32 + l4*8);

    sh8 bpw[4], bpwn[4];
    #pragma unroll
    for (int kk = 0; kk < 4; ++kk)
        bpw[kk] = *(const sh8*)(wp + (hg*64 + l15)*C_ + kk*32 + l4*8);
    for (int nt = 0; nt < 4; ++nt) {
        int ch = hg*64 + nt*16 + l15;
        if (nt < 3) {
            #pragma unroll
            for (int kk = 0; kk < 4; ++kk)
                bpwn[kk] = *(const sh8*)(wp + (ch+16)*C_ + kk*32 + l4*8);
        }
        f32x4 acc = {0.f,0.f,0.f,0.f};
        #pragma unroll
        for (int kk = 0; kk < 4; ++kk)
            acc = __builtin_amdgcn_mfma_f32_16x16x32_bf16(pa[kk], bpw[kk], acc, 0,0,0);
        float pbv = projb[ch];
        #pragma unroll
        for (int r = 0; r < 4; ++r)
            if (pred[r])
                out[tokb[r] + ch] = acc[r] + pbv;   // attn contribution only; x added in mlp
        #pragma unroll
        for (int kk = 0; kk < 4; ++kk) bpw[kk] = bpwn[kk];
    }
}

// ---- mlp v6: vectorized LN2 I/O (float4/short4), rest = r19 structure ----
// LDS: xin f32[64][132] @0 | hv bf16[64][264] @0 (overlay) | outs f32 @0 ;
//      h2 bf16[64][136] @33792 -> total 51200
__global__ __launch_bounds__(512) void mlp_k(
    const float* __restrict__ x,
    float* __restrict__ xio,
    const float* __restrict__ n2g, const float* __restrict__ n2b,
    const float* __restrict__ f1b, const float* __restrict__ f2b,
    const short* __restrict__ w1, const short* __restrict__ w2)
{
    __shared__ char smem[51200];
    float* xin = (float*)smem;               // [64][132]
    short* hv  = (short*)smem;               // [64][264], after xin dies
    float* outs= (float*)smem;               // [64][132], after hv dies
    short* h2  = (short*)(smem + 33792);     // [64][136]

    const int tid = threadIdx.x;
    const int lane = tid & 63, wv = tid >> 6;
    const int l15 = lane & 15, l4 = lane >> 4;
    const int mh = wv & 1, ng = wv >> 1;
    const size_t base = (size_t)blockIdx.x * 64 * C_;

    // stage residual = x + attn (both contiguous full-line reads)
    for (int i = tid; i < 2048; i += 512) {
        float4 vx = ((const float4*)(x + base))[i];
        float4 va = ((const float4*)(xio + base))[i];
        vx.x += va.x; vx.y += va.y; vx.z += va.z; vx.w += va.w;
        int row = i >> 5, col = (i & 31) * 4;
        *(float4*)(xin + row*132 + col) = vx;
    }
    __syncthreads();

    // LN2: 8 threads/token, fully vectorized LDS/global I/O
    {
        int tok = tid >> 3, sub = tid & 7;
        float4 vb[4]; float4 g4[4], b4[4];
        float s = 0.f, sq = 0.f;
        #pragma unroll
        for (int c4 = 0; c4 < 4; ++c4) {
            int ch = sub*16 + c4*4;
            vb[c4] = *(const float4*)(xin + tok*132 + ch);
            g4[c4] = *(const float4*)(n2g + ch);
            b4[c4] = *(const float4*)(n2b + ch);
            s  += vb[c4].x + vb[c4].y + vb[c4].z + vb[c4].w;
            sq += vb[c4].x*vb[c4].x + vb[c4].y*vb[c4].y + vb[c4].z*vb[c4].z + vb[c4].w*vb[c4].w;
        }
        #pragma unroll
        for (int off = 1; off < 8; off <<= 1) {
            s  += __shfl_xor(s, off);
            sq += __shfl_xor(sq, off);
        }
        float mean = s * (1.f/128.f);
        float var  = sq * (1.f/128.f) - mean*mean;
        float rstd = rsqrtf(var + 1e-5f);
        #pragma unroll
        for (int c4 = 0; c4 < 4; ++c4) {
            int ch = sub*16 + c4*4;
            short4 o;
            o.x = f2bs((vb[c4].x - mean)*rstd*g4[c4].x + b4[c4].x);
            o.y = f2bs((vb[c4].y - mean)*rstd*g4[c4].y + b4[c4].y);
            o.z = f2bs((vb[c4].z - mean)*rstd*g4[c4].z + b4[c4].z);
            o.w = f2bs((vb[c4].w - mean)*rstd*g4[c4].w + b4[c4].w);
            *(short4*)(h2 + tok*136 + ch) = o;
        }
    }
    float res[2][2][4];
    #pragma unroll
    for (int mt2 = 0; mt2 < 2; ++mt2)
        #pragma unroll
        for (int nt = 0; nt < 2; ++nt)
            #pragma unroll
            for (int r = 0; r < 4; ++r) {
                int m  = (mh*2 + mt2)*16 + l4*4 + r;
                int ch = ng*32 + nt*16 + l15;
                res[mt2][nt][r] = xin[m*132 + ch];
            }
    __syncthreads();   // xin dead -> hv may overlay

    f32x4 facc[2][2] = {};
    #pragma unroll 1
    for (int chunk = 0; chunk < 2; ++chunk) {
        const int c0 = chunk*256;
        // ---- fc1 + GELU: chunk-local cols ng*64..+63, both m-tiles ----
        {
            sh8 b1[4], b1n[4];
            #pragma unroll
            for (int kk = 0; kk < 4; ++kk)
                b1[kk] = *(const sh8*)(w1 + (size_t)(c0 + ng*64 + l15)*C_ + kk*32 + l4*8);
            for (int t = 0; t < 4; ++t) {
                int n = c0 + ng*64 + t*16 + l15;
                if (t < 3) {
                    #pragma unroll
                    for (int kk = 0; kk < 4; ++kk)
                        b1n[kk] = *(const sh8*)(w1 + (size_t)(n + 16)*C_ + kk*32 + l4*8);
                }
                float bias = f1b[n];
                #pragma unroll
                for (int mt2 = 0; mt2 < 2; ++mt2) {
                    int mrow = (mh*2 + mt2)*16;
                    f32x4 acc = {0.f,0.f,0.f,0.f};
                    #pragma unroll
                    for (int kk = 0; kk < 4; ++kk) {
                        sh8 av = *(const sh8*)(h2 + (mrow + l15)*136 + kk*32 + l4*8);
                        acc = __builtin_amdgcn_mfma_f32_16x16x32_bf16(av, b1[kk], acc, 0,0,0);
                    }
                    #pragma unroll
                    for (int r = 0; r < 4; ++r) {
                        float xv = acc[r] + bias;
                        float g = xv * 0.5f * (1.f + erff(xv * 0.70710678118654752f));
                        hv[(mrow + l4*4 + r)*264 + ng*64 + t*16 + l15] = f2bs(g);
                    }
                }
                #pragma unroll
                for (int kk = 0; kk < 4; ++kk) b1[kk] = b1n[kk];
            }
        }
        __syncthreads();
        // ---- fc2 partial: K = [c0, c0+256), out cols ng*32..+31, both m-tiles ----
        {
            sh8 b2[2], b2n[2];
            #pragma unroll
            for (int nt = 0; nt < 2; ++nt)
                b2[nt] = *(const sh8*)(w2 + (size_t)(ng*32 + nt*16 + l15)*512 + c0 + l4*8);
            for (int ks = 0; ks < 8; ++ks) {
                if (ks < 7) {
                    #pragma unroll
                    for (int nt = 0; nt < 2; ++nt)
                        b2n[nt] = *(const sh8*)(w2 + (size_t)(ng*32 + nt*16 + l15)*512 + c0 + (ks+1)*32 + l4*8);
                }
                #pragma unroll
                for (int mt2 = 0; mt2 < 2; ++mt2) {
                    sh8 av = *(const sh8*)(hv + ((mh*2 + mt2)*16 + l15)*264 + ks*32 + l4*8);
                    facc[mt2][0] = __builtin_amdgcn_mfma_f32_16x16x32_bf16(av, b2[0], facc[mt2][0], 0,0,0);
                    facc[mt2][1] = __builtin_amdgcn_mfma_f32_16x16x32_bf16(av, b2[1], facc[mt2][1], 0,0,0);
                }
                b2[0] = b2n[0]; b2[1] = b2n[1];
            }
        }
        __syncthreads();
    }

    #pragma unroll
    for (int mt2 = 0; mt2 < 2; ++mt2)
        #pragma unroll
        for (int nt = 0; nt < 2; ++nt) {
            int oc = ng*32 + nt*16 + l15;
            float bias = f2b[oc];
            #pragma unroll
            for (int r = 0; r < 4; ++r) {
                int m = (mh*2 + mt2)*16 + l4*4 + r;
                outs[m*132 + oc] = res[mt2][nt][r] + facc[mt2][nt][r] + bias;
            }
        }
    __syncthreads();
    for (int i = tid; i < 2048; i += 512) {
        int row = i >> 5, col = (i & 31) * 4;
        ((float4*)(xio + base))[i] = *(const float4*)(outs + row*132 + col);
    }
}

extern "C" void kernel_launch(void* const* d_in, const int* in_sizes, int n_in,
                              void* d_out, int out_size, void* d_ws, size_t ws_size,
                              hipStream_t stream) {
    const float* x    = (const float*)d_in[0];
    const float* n1g  = (const float*)d_in[1];
    const float* n1b  = (const float*)d_in[2];
    const float* qkvw = (const float*)d_in[3];
    const float* qkvb = (const float*)d_in[4];
    const float* rpb  = (const float*)d_in[5];
    const float* pw   = (const float*)d_in[6];
    const float* pb   = (const float*)d_in[7];
    const float* n2g  = (const float*)d_in[8];
    const float* n2b  = (const float*)d_in[9];
    const float* f1w  = (const float*)d_in[10];
    const float* f1b  = (const float*)d_in[11];
    const float* f2w  = (const float*)d_in[12];
    const float* f2b  = (const float*)d_in[13];

    short* ws = (short*)d_ws;          // bf16 weights + bias table (426 KB)
    const short* wq = ws;
    const short* wp = ws + 49152;
    const short* w1 = ws + 65536;
    const short* w2 = ws + 131072;
    const short* bt = ws + 196608;
    float* xio = (float*)d_out;

    hipLaunchKernelGGL(prep_k, dim3(832), dim3(256), 0, stream, qkvw, pw, f1w, f2w, rpb, ws);
    hipLaunchKernelGGL(win_attn, dim3(B_*NWIN_), dim3(512), 0, stream,
                       x, n1g, n1b, qkvb, bt, pb, wq, wp, xio);
    hipLaunchKernelGGL(mlp_k, dim3(B_*H1_*W1_/64), dim3(512), 0, stream,
                       x, xio, n2g, n2b, f1b, f2b, w1, w2);
}